// Round 1
// baseline (1531.945 us; speedup 1.0000x reference)
//
#include <hip/hip_runtime.h>
#include <math.h>

// Problem constants (B=8, Ci=Co=256, H=W=64, K=3, PAD=1)
#define CI 256
#define CO 256
#define HWN 4096  // H*W

// ---------------------------------------------------------------------------
// Kernel 1: offset (18ch) + modulation (9ch) 3x3 conv over Ci=256.
// Block = one (b, h) row, 256 threads = 4 waves; wave g handles channels
// c = 4t+g; x rows staged in LDS; weight loads are wave-uniform -> scalar.
// Outputs dy, dx, mask planes (mask = 2*sigmoid).
// ---------------------------------------------------------------------------
__global__ __launch_bounds__(256) void k_offmod(
    const float* __restrict__ x, const float* __restrict__ ow,
    const float* __restrict__ ob, const float* __restrict__ mw,
    const float* __restrict__ mb, float* __restrict__ dyb,
    float* __restrict__ dxb, float* __restrict__ mskb) {
  __shared__ float xs[792];   // 4 ch * 3 rows * 66 cols
  __shared__ float ps[6912];  // 64 px * 27 ch * 4 groups
  const int tid = threadIdx.x;
  const int bh = blockIdx.x;
  const int b = bh >> 6, h = bh & 63;
  const int cg = __builtin_amdgcn_readfirstlane(tid >> 6);  // wave id 0..3
  const int px = tid & 63;
  float acc[27];
#pragma unroll
  for (int i = 0; i < 27; ++i) acc[i] = 0.f;
  const float* xb = x + b * (CI * HWN);
  for (int t = 0; t < 64; ++t) {
    __syncthreads();
    for (int i = tid; i < 792; i += 256) {
      int cl = i / 198;
      int rem = i - cl * 198;
      int r = rem / 66;
      int col = rem - r * 66 - 1;
      int hh = h - 1 + r;
      float v = 0.f;
      if (hh >= 0 && hh < 64 && col >= 0 && col < 64)
        v = xb[(4 * t + cl) * HWN + hh * 64 + col];
      xs[i] = v;
    }
    __syncthreads();
    float xv[9];
#pragma unroll
    for (int r = 0; r < 3; ++r)
#pragma unroll
      for (int kx = 0; kx < 3; ++kx)
        xv[r * 3 + kx] = xs[cg * 198 + r * 66 + px + kx];
    const int c = 4 * t + cg;
    const float* owp = ow + c * 9;  // [ch][c][9] -> ch*2304 + c*9 + k
    const float* mwp = mw + c * 9;
#pragma unroll
    for (int ch = 0; ch < 18; ++ch)
#pragma unroll
      for (int k = 0; k < 9; ++k)
        acc[ch] = fmaf(owp[ch * 2304 + k], xv[k], acc[ch]);
#pragma unroll
    for (int ch = 0; ch < 9; ++ch)
#pragma unroll
      for (int k = 0; k < 9; ++k)
        acc[18 + ch] = fmaf(mwp[ch * 2304 + k], xv[k], acc[18 + ch]);
  }
  __syncthreads();
#pragma unroll
  for (int ch = 0; ch < 27; ++ch) ps[(px * 27 + ch) * 4 + cg] = acc[ch];
  __syncthreads();
  for (int i = tid; i < 1728; i += 256) {
    int p2 = i / 27;
    int ch = i - p2 * 27;
    float s = ps[i * 4] + ps[i * 4 + 1] + ps[i * 4 + 2] + ps[i * 4 + 3];
    if (ch < 18) {
      s += ob[ch];
      int k = ch >> 1;  // channel 2k = dy_k, 2k+1 = dx_k
      int o9 = ((b * 9 + k) << 12) + (h << 6) + p2;
      if ((ch & 1) == 0) dyb[o9] = s;
      else dxb[o9] = s;
    } else {
      int k = ch - 18;
      s += mb[k];
      mskb[((b * 9 + k) << 12) + (h << 6) + p2] = 2.f / (1.f + expf(-s));
    }
  }
}

// ---------------------------------------------------------------------------
// Kernel 2: fused gather-GEMM. M=B*H*W=32768, N=Co=256, K=Ci*9=2304.
// Block tile 128 px x 128 o (grid 256x2), 256 threads, 8x8 per thread.
// Bilinear corner table (idx + mask-folded weights) computed once per block.
// Writes pre-BN out + per-(block,o) partial sum/sumsq for BN stats.
// Conv bias is omitted: it cancels exactly in (out - mean(out)).
// ---------------------------------------------------------------------------
__global__ __launch_bounds__(256) void k_main(
    const float* __restrict__ x, const float* __restrict__ wgt,
    const float* __restrict__ dyb, const float* __restrict__ dxb,
    const float* __restrict__ mskb, float* __restrict__ out,
    float* __restrict__ psum, float* __restrict__ psq) {
  __shared__ __align__(16) char smem[64512];
  float4* s_cw = (float4*)smem;              // [9][128] corner weights
  ushort4* s_ci = (ushort4*)(smem + 18432);  // [9][128] corner indices
  float* sA = (float*)(smem + 27648);        // [36][128] gathered samples
  float* sB = (float*)(smem + 46080);        // [36][128] weights (kc-major)
  const int tid = threadIdx.x;
  const int mblk = blockIdx.x;      // 0..255: 128-pixel tile (2 rows of one b)
  const int O0 = blockIdx.y << 7;   // 0 or 128
  const int b = mblk >> 5;
  const int h0 = (mblk & 31) << 1;

  // ---- corner table: 1152 = 9 taps * 128 px ----
  for (int i = tid; i < 1152; i += 256) {
    int k = i >> 7, px = i & 127;
    int h = h0 + (px >> 6), w = px & 63;
    int o9 = ((b * 9 + k) << 12) + (h << 6) + w;
    float m = mskb[o9];
    float py = (float)(h - 1 + k / 3) + dyb[o9];
    float pxf = (float)(w - 1 + k % 3) + dxb[o9];
    float y0f = floorf(py), x0f = floorf(pxf);
    float wy = py - y0f, wx = pxf - x0f;
    int y0 = (int)y0f, x0 = (int)x0f;
    int y1 = y0 + 1, x1 = x0 + 1;
    float w00 = (1.f - wy) * (1.f - wx) * m;
    float w01 = (1.f - wy) * wx * m;
    float w10 = wy * (1.f - wx) * m;
    float w11 = wy * wx * m;
    bool vy0 = ((unsigned)y0 < 64u), vy1 = ((unsigned)y1 < 64u);
    bool vx0 = ((unsigned)x0 < 64u), vx1 = ((unsigned)x1 < 64u);
    if (!(vy0 && vx0)) w00 = 0.f;
    if (!(vy0 && vx1)) w01 = 0.f;
    if (!(vy1 && vx0)) w10 = 0.f;
    if (!(vy1 && vx1)) w11 = 0.f;
    int y0c = min(max(y0, 0), 63), y1c = min(max(y1, 0), 63);
    int x0c = min(max(x0, 0), 63), x1c = min(max(x1, 0), 63);
    s_cw[i] = make_float4(w00, w01, w10, w11);
    s_ci[i] = make_ushort4((unsigned short)(y0c * 64 + x0c),
                           (unsigned short)(y0c * 64 + x1c),
                           (unsigned short)(y1c * 64 + x0c),
                           (unsigned short)(y1c * 64 + x1c));
  }

  float acc[8][8];
#pragma unroll
  for (int i = 0; i < 8; ++i)
#pragma unroll
    for (int j = 0; j < 8; ++j) acc[i][j] = 0.f;
  const int ty = tid >> 4, tx = tid & 15;
  const float* xb = x + b * (CI * HWN);

  for (int c0 = 0; c0 < 256; c0 += 4) {
    __syncthreads();
    // ---- stage A: 36 kc-rows x 128 px, gathered bilinear samples ----
    for (int t = 0; t < 18; ++t) {
      int vid = t * 256 + tid;
      int kc = vid >> 7, px = vid & 127;
      int cl = kc / 9;
      int kk = kc - cl * 9;
      float4 cw = s_cw[kk * 128 + px];
      ushort4 ci = s_ci[kk * 128 + px];
      const float* xp = xb + (c0 + cl) * HWN;
      float v = cw.x * xp[ci.x];
      v = fmaf(cw.y, xp[ci.y], v);
      v = fmaf(cw.z, xp[ci.z], v);
      v = fmaf(cw.w, xp[ci.w], v);
      sA[kc * 128 + px] = v;
    }
    // ---- stage B: weight[o][c0..c0+3][0..8] -> sB[kc][o], contiguous runs ----
    {
      int o_l = tid & 127;
      int part = tid >> 7;  // wave-uniform branch
      const float* wp = wgt + (O0 + o_l) * 2304 + c0 * 9;
      if (part == 0) {
#pragma unroll
        for (int f = 0; f < 4; ++f) {
          float4 v = *(const float4*)(wp + f * 4);
          int kc = f * 4;
          sB[kc * 128 + o_l] = v.x;
          sB[(kc + 1) * 128 + o_l] = v.y;
          sB[(kc + 2) * 128 + o_l] = v.z;
          sB[(kc + 3) * 128 + o_l] = v.w;
        }
      } else {
#pragma unroll
        for (int f = 0; f < 5; ++f) {
          float4 v = *(const float4*)(wp + 16 + f * 4);
          int kc = 16 + f * 4;
          sB[kc * 128 + o_l] = v.x;
          sB[(kc + 1) * 128 + o_l] = v.y;
          sB[(kc + 2) * 128 + o_l] = v.z;
          sB[(kc + 3) * 128 + o_l] = v.w;
        }
      }
    }
    __syncthreads();
    // ---- 36 K-steps of 8x8 outer product ----
#pragma unroll
    for (int kc = 0; kc < 36; ++kc) {
      const float4 a0 = *(const float4*)(sA + kc * 128 + (ty << 3));
      const float4 a1 = *(const float4*)(sA + kc * 128 + (ty << 3) + 4);
      const float4 b0 = *(const float4*)(sB + kc * 128 + (tx << 3));
      const float4 b1 = *(const float4*)(sB + kc * 128 + (tx << 3) + 4);
      float av[8] = {a0.x, a0.y, a0.z, a0.w, a1.x, a1.y, a1.z, a1.w};
      float bv[8] = {b0.x, b0.y, b0.z, b0.w, b1.x, b1.y, b1.z, b1.w};
#pragma unroll
      for (int i = 0; i < 8; ++i)
#pragma unroll
        for (int j = 0; j < 8; ++j)
          acc[i][j] = fmaf(bv[i], av[j], acc[i][j]);
    }
  }

  // ---- store pre-BN out + per-thread partial stats ----
  const int hrow = h0 + (ty >> 3);
  const int w0 = (ty & 7) << 3;
  float ls[8], lq[8];
#pragma unroll
  for (int i = 0; i < 8; ++i) {
    int o = O0 + (tx << 3) + i;
    float* op = out + ((b * 256 + o) << 12) + (hrow << 6) + w0;
    *(float4*)op = make_float4(acc[i][0], acc[i][1], acc[i][2], acc[i][3]);
    *(float4*)(op + 4) = make_float4(acc[i][4], acc[i][5], acc[i][6], acc[i][7]);
    float s = 0.f, q = 0.f;
#pragma unroll
    for (int j = 0; j < 8; ++j) {
      s += acc[i][j];
      q = fmaf(acc[i][j], acc[i][j], q);
    }
    ls[i] = s;
    lq[i] = q;
  }
  __syncthreads();  // sA reads of last chunk done; reuse as reduction buffer
  float* red_s = sA;
  float* red_q = sA + 2176;  // 128*17
#pragma unroll
  for (int i = 0; i < 8; ++i) {
    red_s[((tx << 3) + i) * 17 + ty] = ls[i];
    red_q[((tx << 3) + i) * 17 + ty] = lq[i];
  }
  __syncthreads();
  if (tid < 128) {
    float s = 0.f, q = 0.f;
#pragma unroll
    for (int t = 0; t < 16; ++t) {
      s += red_s[tid * 17 + t];
      q += red_q[tid * 17 + t];
    }
    psum[(O0 + tid) * 256 + mblk] = s;
    psq[(O0 + tid) * 256 + mblk] = q;
  }
}

// ---------------------------------------------------------------------------
// Kernel 3: per-channel stats -> scale/shift. 256 blocks x 64 threads.
// ---------------------------------------------------------------------------
__global__ __launch_bounds__(64) void k_stats(
    const float* __restrict__ psum, const float* __restrict__ psq,
    const float* __restrict__ gamma, const float* __restrict__ beta,
    float* __restrict__ scale, float* __restrict__ shift) {
  const int o = blockIdx.x;
  const int t = threadIdx.x;
  float s = psum[o * 256 + t] + psum[o * 256 + t + 64] +
            psum[o * 256 + t + 128] + psum[o * 256 + t + 192];
  float q = psq[o * 256 + t] + psq[o * 256 + t + 64] +
            psq[o * 256 + t + 128] + psq[o * 256 + t + 192];
#pragma unroll
  for (int off = 32; off > 0; off >>= 1) {
    s += __shfl_down(s, off, 64);
    q += __shfl_down(q, off, 64);
  }
  if (t == 0) {
    const float inv_n = 1.f / 32768.f;
    float mean = s * inv_n;
    float var = fmaf(-mean, mean, q * inv_n);
    float sc = gamma[o] * rsqrtf(var + 1e-5f);
    scale[o] = sc;
    shift[o] = fmaf(-mean, sc, beta[o]);
  }
}

// ---------------------------------------------------------------------------
// Kernel 4: in-place BN + ReLU over d_out (float4 elementwise).
// ---------------------------------------------------------------------------
__global__ __launch_bounds__(256) void k_bnrelu(
    float* __restrict__ out, const float* __restrict__ scale,
    const float* __restrict__ shift) {
  int idx = blockIdx.x * 256 + threadIdx.x;  // float4 index, exact cover
  int o = (idx >> 10) & 255;                 // (idx*4)>>12 & 255
  float sc = scale[o], sh = shift[o];
  float4 v = ((float4*)out)[idx];
  v.x = fmaxf(fmaf(v.x, sc, sh), 0.f);
  v.y = fmaxf(fmaf(v.y, sc, sh), 0.f);
  v.z = fmaxf(fmaf(v.z, sc, sh), 0.f);
  v.w = fmaxf(fmaf(v.w, sc, sh), 0.f);
  ((float4*)out)[idx] = v;
}

extern "C" void kernel_launch(void* const* d_in, const int* in_sizes, int n_in,
                              void* d_out, int out_size, void* d_ws,
                              size_t ws_size, hipStream_t stream) {
  const float* x = (const float*)d_in[0];
  const float* ow = (const float*)d_in[1];
  const float* ob = (const float*)d_in[2];
  const float* mw = (const float*)d_in[3];
  const float* mb = (const float*)d_in[4];
  const float* wgt = (const float*)d_in[5];
  // d_in[6] = conv bias: cancels exactly in BN (out - mean(out)), skipped.
  const float* gamma = (const float*)d_in[7];
  const float* beta = (const float*)d_in[8];
  float* out = (float*)d_out;

  // workspace layout (floats): needs ~3.9 MB
  float* ws = (float*)d_ws;
  float* dyb = ws;                  // 8*9*4096 = 294912
  float* dxb = dyb + 294912;        // 294912
  float* mskb = dxb + 294912;       // 294912
  float* psum = mskb + 294912;      // 256*256 = 65536
  float* psq = psum + 65536;        // 65536
  float* scale = psq + 65536;       // 256
  float* shift = scale + 256;       // 256

  k_offmod<<<512, 256, 0, stream>>>(x, ow, ob, mw, mb, dyb, dxb, mskb);
  k_main<<<dim3(256, 2), 256, 0, stream>>>(x, wgt, dyb, dxb, mskb, out, psum,
                                           psq);
  k_stats<<<256, 64, 0, stream>>>(psum, psq, gamma, beta, scale, shift);
  k_bnrelu<<<8192, 256, 0, stream>>>(out, scale, shift);
}

// Round 2
// 543.888 us; speedup vs baseline: 2.8167x; 2.8167x over previous
//
#include <hip/hip_runtime.h>
#include <math.h>

#define CI 256
#define CO 256
#define HWN 4096  // H*W

typedef short bf16x8 __attribute__((ext_vector_type(8)));
typedef float f32x4 __attribute__((ext_vector_type(4)));

__device__ inline unsigned pk2(float a, float b) {  // RNE pack 2 f32 -> 2 bf16
  unsigned ua = __float_as_uint(a), ub = __float_as_uint(b);
  ua += 0x7fff + ((ua >> 16) & 1);
  ub += 0x7fff + ((ub >> 16) & 1);
  return (ua >> 16) | (ub & 0xffff0000u);
}

// ---------------------------------------------------------------------------
// Kernel 1: offset (18ch) + modulation (9ch) 3x3 conv over Ci=256. Unchanged.
// ---------------------------------------------------------------------------
__global__ __launch_bounds__(256) void k_offmod(
    const float* __restrict__ x, const float* __restrict__ ow,
    const float* __restrict__ ob, const float* __restrict__ mw,
    const float* __restrict__ mb, float* __restrict__ dyb,
    float* __restrict__ dxb, float* __restrict__ mskb) {
  __shared__ float xs[792];
  __shared__ float ps[6912];
  const int tid = threadIdx.x;
  const int bh = blockIdx.x;
  const int b = bh >> 6, h = bh & 63;
  const int cg = __builtin_amdgcn_readfirstlane(tid >> 6);
  const int px = tid & 63;
  float acc[27];
#pragma unroll
  for (int i = 0; i < 27; ++i) acc[i] = 0.f;
  const float* xb = x + b * (CI * HWN);
  for (int t = 0; t < 64; ++t) {
    __syncthreads();
    for (int i = tid; i < 792; i += 256) {
      int cl = i / 198;
      int rem = i - cl * 198;
      int r = rem / 66;
      int col = rem - r * 66 - 1;
      int hh = h - 1 + r;
      float v = 0.f;
      if (hh >= 0 && hh < 64 && col >= 0 && col < 64)
        v = xb[(4 * t + cl) * HWN + hh * 64 + col];
      xs[i] = v;
    }
    __syncthreads();
    float xv[9];
#pragma unroll
    for (int r = 0; r < 3; ++r)
#pragma unroll
      for (int kx = 0; kx < 3; ++kx)
        xv[r * 3 + kx] = xs[cg * 198 + r * 66 + px + kx];
    const int c = 4 * t + cg;
    const float* owp = ow + c * 9;
    const float* mwp = mw + c * 9;
#pragma unroll
    for (int ch = 0; ch < 18; ++ch)
#pragma unroll
      for (int k = 0; k < 9; ++k)
        acc[ch] = fmaf(owp[ch * 2304 + k], xv[k], acc[ch]);
#pragma unroll
    for (int ch = 0; ch < 9; ++ch)
#pragma unroll
      for (int k = 0; k < 9; ++k)
        acc[18 + ch] = fmaf(mwp[ch * 2304 + k], xv[k], acc[18 + ch]);
  }
  __syncthreads();
#pragma unroll
  for (int ch = 0; ch < 27; ++ch) ps[(px * 27 + ch) * 4 + cg] = acc[ch];
  __syncthreads();
  for (int i = tid; i < 1728; i += 256) {
    int p2 = i / 27;
    int ch = i - p2 * 27;
    float s = ps[i * 4] + ps[i * 4 + 1] + ps[i * 4 + 2] + ps[i * 4 + 3];
    if (ch < 18) {
      s += ob[ch];
      int k = ch >> 1;
      int o9 = ((b * 9 + k) << 12) + (h << 6) + p2;
      if ((ch & 1) == 0) dyb[o9] = s;
      else dxb[o9] = s;
    } else {
      int k = ch - 18;
      s += mb[k];
      mskb[((b * 9 + k) << 12) + (h << 6) + p2] = 2.f / (1.f + expf(-s));
    }
  }
}

// ---------------------------------------------------------------------------
// Kernel 2: bf16-MFMA gather-GEMM. Block = 64 px (one image row) x 256 out,
// 512 threads / 8 waves, grid 512 (= b*64+h). K = 2304 = 36 chunks x 64.
// LDS: corner tables + sA[64][64]bf16 + sB[256][64]bf16, XOR-swizzled
// (16B slot ^= row&7) for conflict-free ds_read_b128 fragments.
// Wave w: n in [w*32, w*32+32), all 64 px: acc[4 mfrag][2 nfrag] f32x4.
// Epilogue: BN partials from registers; C transposed via LDS (stride 65)
// for coalesced float4 stores.
// ---------------------------------------------------------------------------
__global__ __launch_bounds__(512, 4) void k_main(
    const float* __restrict__ x, const float* __restrict__ wgt,
    const float* __restrict__ dyb, const float* __restrict__ dxb,
    const float* __restrict__ mskb, float* __restrict__ out,
    float* __restrict__ psum, float* __restrict__ psq) {
  __shared__ __align__(16) char smem[54784];
  float4* s_cw = (float4*)smem;             // [9][64] corner weights, 9216 B
  ushort4* s_ci = (ushort4*)(smem + 9216);  // [9][64] corner idx, 4608 B
  char* sA = smem + 13824;                  // 64x64 bf16 = 8192 B
  char* sB = smem + 22016;                  // 256x64 bf16 = 32768 B
  float* tr = (float*)(smem + 13824);       // reuse: 128*65*4 = 33280 B

  const int tid = threadIdx.x;
  const int mblk = blockIdx.x;  // b*64 + h
  const int b = mblk >> 6, h = mblk & 63;
  const int lane = tid & 63;
  const int wv = tid >> 6;

  // ---- corner table: 9 taps * 64 px ----
  for (int i = tid; i < 576; i += 512) {
    int k = i >> 6, pxi = i & 63;
    int o9 = ((b * 9 + k) << 12) + (h << 6) + pxi;
    float m = mskb[o9];
    float py = (float)(h - 1 + k / 3) + dyb[o9];
    float pxf = (float)(pxi - 1 + k % 3) + dxb[o9];
    float y0f = floorf(py), x0f = floorf(pxf);
    float wy = py - y0f, wx = pxf - x0f;
    int y0 = (int)y0f, x0 = (int)x0f;
    int y1 = y0 + 1, x1 = x0 + 1;
    float w00 = (1.f - wy) * (1.f - wx) * m;
    float w01 = (1.f - wy) * wx * m;
    float w10 = wy * (1.f - wx) * m;
    float w11 = wy * wx * m;
    bool vy0 = ((unsigned)y0 < 64u), vy1 = ((unsigned)y1 < 64u);
    bool vx0 = ((unsigned)x0 < 64u), vx1 = ((unsigned)x1 < 64u);
    if (!(vy0 && vx0)) w00 = 0.f;
    if (!(vy0 && vx1)) w01 = 0.f;
    if (!(vy1 && vx0)) w10 = 0.f;
    if (!(vy1 && vx1)) w11 = 0.f;
    int y0c = min(max(y0, 0), 63), y1c = min(max(y1, 0), 63);
    int x0c = min(max(x0, 0), 63), x1c = min(max(x1, 0), 63);
    s_cw[i] = make_float4(w00, w01, w10, w11);
    s_ci[i] = make_ushort4((unsigned short)(y0c * 64 + x0c),
                           (unsigned short)(y0c * 64 + x1c),
                           (unsigned short)(y1c * 64 + x0c),
                           (unsigned short)(y1c * 64 + x1c));
  }

  f32x4 acc[4][2];
#pragma unroll
  for (int mf = 0; mf < 4; ++mf)
#pragma unroll
    for (int nf = 0; nf < 2; ++nf) acc[mf][nf] = (f32x4){0.f, 0.f, 0.f, 0.f};

  const float* xb = x + b * (CI * HWN);
  const int px = lane;       // A-staging: lane = pixel
  const int kcg = wv;        // A-staging: wave = 8-kc group
  const int o_st = tid >> 1; // B-staging row
  const int half = tid & 1;
  const float* wrow = wgt + o_st * 2304 + (half << 5);

  for (int ch = 0; ch < 36; ++ch) {
    __syncthreads();  // fragment reads of previous chunk complete
    // ---- stage A: 64 px x 64 kc gathered bilinear samples (2 half passes) ----
    {
      int kcbase = ch * 64 + (kcg << 3);
      int aslot = (px << 7) + ((kcg ^ (px & 7)) << 4);
#pragma unroll
      for (int hp = 0; hp < 2; ++hp) {
        unsigned pk[2];
#pragma unroll
        for (int j2 = 0; j2 < 2; ++j2) {
          float vv[2];
#pragma unroll
          for (int u = 0; u < 2; ++u) {
            int kc = kcbase + hp * 4 + j2 * 2 + u;
            int c = kc / 9;
            int k = kc - c * 9;
            float4 w4 = s_cw[(k << 6) + px];
            ushort4 i4 = s_ci[(k << 6) + px];
            const float* xp = xb + (c << 12);
            float v = w4.x * xp[i4.x];
            v = fmaf(w4.y, xp[i4.y], v);
            v = fmaf(w4.z, xp[i4.z], v);
            vv[u] = fmaf(w4.w, xp[i4.w], v);
          }
          pk[j2] = pk2(vv[0], vv[1]);
        }
        *(uint2*)(sA + aslot + (hp << 3)) = make_uint2(pk[0], pk[1]);
      }
    }
    // ---- stage B: 256 out x 64 kc of weights -> bf16 ----
    {
      const float* wp = wrow + ch * 64;
#pragma unroll
      for (int q = 0; q < 4; ++q) {
        float4 v0 = *(const float4*)(wp + q * 8);
        float4 v1 = *(const float4*)(wp + q * 8 + 4);
        int slot = ((half << 2) + q) ^ (o_st & 7);
        *(uint4*)(sB + (o_st << 7) + (slot << 4)) =
            make_uint4(pk2(v0.x, v0.y), pk2(v0.z, v0.w), pk2(v1.x, v1.y),
                       pk2(v1.z, v1.w));
      }
    }
    __syncthreads();
    // ---- MFMA: 2 k-steps x 4 mfrag x 2 nfrag ----
#pragma unroll
    for (int ks = 0; ks < 2; ++ks) {
      bf16x8 af[4], bfr[2];
#pragma unroll
      for (int mf = 0; mf < 4; ++mf) {
        int row = (mf << 4) + (lane & 15);
        int slot = ((ks << 2) + (lane >> 4)) ^ (row & 7);
        af[mf] = *(bf16x8*)(sA + (row << 7) + (slot << 4));
      }
#pragma unroll
      for (int nf = 0; nf < 2; ++nf) {
        int row = (wv << 5) + (nf << 4) + (lane & 15);
        int slot = ((ks << 2) + (lane >> 4)) ^ (row & 7);
        bfr[nf] = *(bf16x8*)(sB + (row << 7) + (slot << 4));
      }
#pragma unroll
      for (int mf = 0; mf < 4; ++mf)
#pragma unroll
        for (int nf = 0; nf < 2; ++nf)
          acc[mf][nf] = __builtin_amdgcn_mfma_f32_16x16x32_bf16(
              af[mf], bfr[nf], acc[mf][nf], 0, 0, 0);
    }
  }

  // ---- BN partial stats from registers ----
#pragma unroll
  for (int nf = 0; nf < 2; ++nf) {
    float s = 0.f, q = 0.f;
#pragma unroll
    for (int mf = 0; mf < 4; ++mf)
#pragma unroll
      for (int r = 0; r < 4; ++r) {
        float v = acc[mf][nf][r];
        s += v;
        q = fmaf(v, v, q);
      }
    s += __shfl_down(s, 32);
    q += __shfl_down(q, 32);
    s += __shfl_down(s, 16);
    q += __shfl_down(q, 16);
    if (lane < 16) {
      int o = (wv << 5) + (nf << 4) + lane;
      psum[(o << 9) + mblk] = s;
      psq[(o << 9) + mblk] = q;
    }
  }

  // ---- store via LDS transpose, 2 passes of 128 o-rows ----
  __syncthreads();
  for (int p = 0; p < 2; ++p) {
    if ((wv >> 2) == p) {
#pragma unroll
      for (int mf = 0; mf < 4; ++mf)
#pragma unroll
        for (int nf = 0; nf < 2; ++nf) {
          int ro = ((wv & 3) << 5) + (nf << 4) + (lane & 15);
#pragma unroll
          for (int r = 0; r < 4; ++r)
            tr[ro * 65 + (mf << 4) + ((lane >> 4) << 2) + r] = acc[mf][nf][r];
        }
    }
    __syncthreads();
#pragma unroll
    for (int it = 0; it < 4; ++it) {
      int idx = tid + (it << 9);
      int ro = idx >> 4, qd = idx & 15;
      float4 v = make_float4(tr[ro * 65 + qd * 4], tr[ro * 65 + qd * 4 + 1],
                             tr[ro * 65 + qd * 4 + 2], tr[ro * 65 + qd * 4 + 3]);
      *(float4*)(out + (((b << 8) + (p << 7) + ro) << 12) + (h << 6) +
                 (qd << 2)) = v;
    }
    __syncthreads();
  }
}

// ---------------------------------------------------------------------------
// Kernel 3: per-channel stats -> scale/shift (512 partials per channel now).
// ---------------------------------------------------------------------------
__global__ __launch_bounds__(64) void k_stats(
    const float* __restrict__ psum, const float* __restrict__ psq,
    const float* __restrict__ gamma, const float* __restrict__ beta,
    float* __restrict__ scale, float* __restrict__ shift) {
  const int o = blockIdx.x;
  const int t = threadIdx.x;
  float s = 0.f, q = 0.f;
#pragma unroll
  for (int i = 0; i < 8; ++i) {
    s += psum[(o << 9) + t + (i << 6)];
    q += psq[(o << 9) + t + (i << 6)];
  }
#pragma unroll
  for (int off = 32; off > 0; off >>= 1) {
    s += __shfl_down(s, off, 64);
    q += __shfl_down(q, off, 64);
  }
  if (t == 0) {
    const float inv_n = 1.f / 32768.f;
    float mean = s * inv_n;
    float var = fmaf(-mean, mean, q * inv_n);
    float sc = gamma[o] * rsqrtf(var + 1e-5f);
    scale[o] = sc;
    shift[o] = fmaf(-mean, sc, beta[o]);
  }
}

// ---------------------------------------------------------------------------
// Kernel 4: in-place BN + ReLU over d_out (float4 elementwise).
// ---------------------------------------------------------------------------
__global__ __launch_bounds__(256) void k_bnrelu(
    float* __restrict__ out, const float* __restrict__ scale,
    const float* __restrict__ shift) {
  int idx = blockIdx.x * 256 + threadIdx.x;
  int o = (idx >> 10) & 255;
  float sc = scale[o], sh = shift[o];
  float4 v = ((float4*)out)[idx];
  v.x = fmaxf(fmaf(v.x, sc, sh), 0.f);
  v.y = fmaxf(fmaf(v.y, sc, sh), 0.f);
  v.z = fmaxf(fmaf(v.z, sc, sh), 0.f);
  v.w = fmaxf(fmaf(v.w, sc, sh), 0.f);
  ((float4*)out)[idx] = v;
}

extern "C" void kernel_launch(void* const* d_in, const int* in_sizes, int n_in,
                              void* d_out, int out_size, void* d_ws,
                              size_t ws_size, hipStream_t stream) {
  const float* x = (const float*)d_in[0];
  const float* ow = (const float*)d_in[1];
  const float* ob = (const float*)d_in[2];
  const float* mw = (const float*)d_in[3];
  const float* mb = (const float*)d_in[4];
  const float* wgt = (const float*)d_in[5];
  // d_in[6] = conv bias: cancels exactly in BN (out - mean(out)), skipped.
  const float* gamma = (const float*)d_in[7];
  const float* beta = (const float*)d_in[8];
  float* out = (float*)d_out;

  float* ws = (float*)d_ws;
  float* dyb = ws;                  // 294912
  float* dxb = dyb + 294912;        // 294912
  float* mskb = dxb + 294912;       // 294912
  float* psum = mskb + 294912;      // 256*512 = 131072
  float* psq = psum + 131072;       // 131072
  float* scale = psq + 131072;      // 256
  float* shift = scale + 256;       // 256

  k_offmod<<<512, 256, 0, stream>>>(x, ow, ob, mw, mb, dyb, dxb, mskb);
  k_main<<<512, 512, 0, stream>>>(x, wgt, dyb, dxb, mskb, out, psum, psq);
  k_stats<<<256, 64, 0, stream>>>(psum, psq, gamma, beta, scale, shift);
  k_bnrelu<<<8192, 256, 0, stream>>>(out, scale, shift);
}